// Round 1
// baseline (259.416 us; speedup 1.0000x reference)
//
#include <hip/hip_runtime.h>
#include <hip/hip_bf16.h>
#include <math.h>

typedef __attribute__((ext_vector_type(8))) short short8;
typedef __attribute__((ext_vector_type(4))) float f32x4;

#define T_TOK 2048
#define D_DIM 512
#define F_DIM 2048
#define E_NUM 8

__device__ __forceinline__ unsigned short f2bf(float f) {
  union { float f; unsigned u; } c; c.f = f;
  unsigned u = c.u;
  return (unsigned short)((u + 0x7fffu + ((u >> 16) & 1u)) >> 16);
}

__device__ __forceinline__ void gld16(const void* g, void* l) {
  __builtin_amdgcn_global_load_lds((const __attribute__((address_space(1))) int*)g,
                                   (__attribute__((address_space(3))) int*)l, 16, 0, 0);
}

// ---------------- routing: logits + top-2 + weight ----------------
__global__ __launch_bounds__(256) void k_route(const float* __restrict__ x,
                                               const float* __restrict__ Wg,
                                               int* __restrict__ jbuf,
                                               float* __restrict__ wbuf) {
  int t = blockIdx.x * 256 + threadIdx.x;
  const float4* xr = (const float4*)(x + (size_t)t * D_DIM);
  float acc[8];
#pragma unroll
  for (int e = 0; e < 8; ++e) acc[e] = 0.f;
  for (int d4 = 0; d4 < D_DIM / 4; ++d4) {
    float4 xv = xr[d4];
    const float* xs = (const float*)&xv;
#pragma unroll
    for (int q = 0; q < 4; ++q) {
      const float4* wr = (const float4*)(Wg + (size_t)(d4 * 4 + q) * 8);
      float4 w0 = wr[0], w1 = wr[1];
      acc[0] += xs[q] * w0.x; acc[1] += xs[q] * w0.y;
      acc[2] += xs[q] * w0.z; acc[3] += xs[q] * w0.w;
      acc[4] += xs[q] * w1.x; acc[5] += xs[q] * w1.y;
      acc[6] += xs[q] * w1.z; acc[7] += xs[q] * w1.w;
    }
  }
  // top-2, ties -> lower index (jax.lax.top_k semantics): strict > in ascending scan
  float l0 = -1e30f, l1 = -1e30f; int i0 = 0, i1 = 0;
#pragma unroll
  for (int e = 0; e < 8; ++e) {
    float l = acc[e];
    if (l > l0) { l1 = l0; i1 = i0; l0 = l; i0 = e; }
    else if (l > l1) { l1 = l; i1 = e; }
  }
  // reference overwrites: winning expert = max selected index; weight = its softmax share
  int j; float w;
  if (i0 > i1) { j = i0; w = 1.f / (1.f + expf(l1 - l0)); }
  else         { j = i1; w = 1.f / (1.f + expf(l0 - l1)); }
  jbuf[t] = j; wbuf[t] = w;
}

// ---------------- bucket: counts, bases, compact token lists ----------------
__global__ __launch_bounds__(256) void k_bucket(const int* __restrict__ jbuf,
                                                int* __restrict__ cntp,
                                                int* __restrict__ basep,
                                                int* __restrict__ list) {
  __shared__ int scnt[8], scur[8];
  int tid = threadIdx.x;
  if (tid < 8) scnt[tid] = 0;
  __syncthreads();
  for (int t = tid; t < T_TOK; t += 256) atomicAdd(&scnt[jbuf[t]], 1);
  __syncthreads();
  if (tid == 0) {
    int run = 0;
    for (int e = 0; e < 8; ++e) {
      scur[e] = run;
      cntp[e] = scnt[e]; basep[e] = run;
      run += scnt[e];
    }
  }
  __syncthreads();
  for (int t = tid; t < T_TOK; t += 256) {
    int j = jbuf[t];
    int p = atomicAdd(&scur[j], 1);
    list[p] = t;
  }
}

// ---------------- convert x -> bf16 ----------------
__global__ __launch_bounds__(256) void k_cvt_x(const float* __restrict__ x,
                                               unsigned short* __restrict__ xb) {
  int i = (blockIdx.x * 256 + threadIdx.x) * 4;
  float4 v = *(const float4*)(x + i);
  ushort4 o;
  o.x = f2bf(v.x); o.y = f2bf(v.y); o.z = f2bf(v.z); o.w = f2bf(v.w);
  *(ushort4*)(xb + i) = o;
}

// ---------------- transpose f32 [Z][R][C] -> bf16 [Z][C][R] ----------------
__global__ __launch_bounds__(256) void k_tr(const float* __restrict__ in,
                                            unsigned short* __restrict__ out,
                                            int R, int C) {
  __shared__ float tile[32][33];
  int z = blockIdx.z;
  int c0 = blockIdx.x * 32, r0 = blockIdx.y * 32;
  const float* ip = in + (size_t)z * R * C;
  unsigned short* op = out + (size_t)z * R * C;
  int tx = threadIdx.x & 31, ty = threadIdx.x >> 5;
#pragma unroll
  for (int k = 0; k < 4; ++k)
    tile[ty + 8 * k][tx] = ip[(size_t)(r0 + ty + 8 * k) * C + (c0 + tx)];
  __syncthreads();
#pragma unroll
  for (int k = 0; k < 4; ++k)
    op[(size_t)(c0 + ty + 8 * k) * R + (r0 + tx)] = f2bf(tile[tx][ty + 8 * k]);
}

// ---------------- pass 1: u = X@W1, v = X@W3, h = silu(u)*v (grouped, gathered A) --------
__global__ __launch_bounds__(256) void k_ffn1(const unsigned short* __restrict__ xb,
                                              const unsigned short* __restrict__ w1t,
                                              const unsigned short* __restrict__ w3t,
                                              const int* __restrict__ cntp,
                                              const int* __restrict__ basep,
                                              const int* __restrict__ list,
                                              unsigned short* __restrict__ hbuf) {
  int e = blockIdx.z, mt = blockIdx.x, nt = blockIdx.y;
  int cnt = cntp[e];
  if (mt * 128 >= cnt) return;
  int base = basep[e];
  __shared__ unsigned short sA[128 * 64], sB1[128 * 64], sB3[128 * 64];
  int tid = threadIdx.x, wv = tid >> 6, l = tid & 63;
  int wr = wv >> 1, wc = wv & 1;
  int colg = l & 7;
  const unsigned short* gA[4]; const unsigned short* gB1[4]; const unsigned short* gB3[4];
#pragma unroll
  for (int s = 0; s < 4; ++s) {
    int r = s * 32 + wv * 8 + (l >> 3);
    int rr = mt * 128 + r; if (rr >= cnt) rr = cnt - 1;   // clamp: garbage rows -> dup valid token
    int tok = list[base + rr];
    gA[s] = xb + (size_t)tok * D_DIM + colg * 8;
    int f = nt * 128 + r;
    gB1[s] = w1t + ((size_t)e * F_DIM + f) * D_DIM + colg * 8;
    gB3[s] = w3t + ((size_t)e * F_DIM + f) * D_DIM + colg * 8;
  }
  f32x4 au[4][4], av[4][4];
#pragma unroll
  for (int i = 0; i < 4; ++i)
#pragma unroll
    for (int j = 0; j < 4; ++j) {
      au[i][j] = (f32x4){0.f, 0.f, 0.f, 0.f};
      av[i][j] = (f32x4){0.f, 0.f, 0.f, 0.f};
    }

  for (int ks = 0; ks < D_DIM / 64; ++ks) {
    __syncthreads();
#pragma unroll
    for (int s = 0; s < 4; ++s) {
      int lo = s * 2048 + wv * 512;  // LDS element offset, wave-uniform
      gld16(gA[s] + ks * 64, sA + lo);
      gld16(gB1[s] + ks * 64, sB1 + lo);
      gld16(gB3[s] + ks * 64, sB3 + lo);
    }
    __syncthreads();
#pragma unroll
    for (int kk = 0; kk < 2; ++kk) {
      int ko = kk * 32 + (l >> 4) * 8;
      short8 a[4], b1[4], b3[4];
#pragma unroll
      for (int i = 0; i < 4; ++i)
        a[i] = *(const short8*)(sA + (wr * 64 + i * 16 + (l & 15)) * 64 + ko);
#pragma unroll
      for (int j = 0; j < 4; ++j) {
        b1[j] = *(const short8*)(sB1 + (wc * 64 + j * 16 + (l & 15)) * 64 + ko);
        b3[j] = *(const short8*)(sB3 + (wc * 64 + j * 16 + (l & 15)) * 64 + ko);
      }
#pragma unroll
      for (int i = 0; i < 4; ++i)
#pragma unroll
        for (int j = 0; j < 4; ++j) {
          au[i][j] = __builtin_amdgcn_mfma_f32_16x16x32_bf16(a[i], b1[j], au[i][j], 0, 0, 0);
          av[i][j] = __builtin_amdgcn_mfma_f32_16x16x32_bf16(a[i], b3[j], av[i][j], 0, 0, 0);
        }
    }
  }
  // epilogue: h = silu(u) * v, write bf16 at compacted rows
  int cloc = l & 15, rb = (l >> 4) * 4;
#pragma unroll
  for (int i = 0; i < 4; ++i) {
#pragma unroll
    for (int j = 0; j < 4; ++j) {
      int col = nt * 128 + wc * 64 + j * 16 + cloc;
#pragma unroll
      for (int r = 0; r < 4; ++r) {
        int rl = mt * 128 + wr * 64 + i * 16 + rb + r;
        if (rl < cnt) {
          float uu = au[i][j][r], vv = av[i][j][r];
          float hh = (uu / (1.f + expf(-uu))) * vv;
          hbuf[(size_t)(base + rl) * F_DIM + col] = f2bf(hh);
        }
      }
    }
  }
}

// ---------------- pass 2: y = h @ W2, out[tok] = w * y ----------------
__global__ __launch_bounds__(256) void k_ffn2(const unsigned short* __restrict__ hbuf,
                                              const unsigned short* __restrict__ w2t,
                                              const int* __restrict__ cntp,
                                              const int* __restrict__ basep,
                                              const int* __restrict__ list,
                                              const float* __restrict__ wbuf,
                                              float* __restrict__ out) {
  int e = blockIdx.z, mt = blockIdx.x, nt = blockIdx.y;
  int cnt = cntp[e];
  if (mt * 32 >= cnt) return;
  int base = basep[e];
  __shared__ unsigned short sA[32 * 64], sB[128 * 64];
  int tid = threadIdx.x, wv = tid >> 6, l = tid & 63;
  int colg = l & 7;
  int ra = wv * 8 + (l >> 3);
  int crow = base + mt * 32 + ra; if (crow > T_TOK - 1) crow = T_TOK - 1;
  const unsigned short* gA = hbuf + (size_t)crow * F_DIM + colg * 8;
  const unsigned short* gB[4];
#pragma unroll
  for (int s = 0; s < 4; ++s) {
    int n = s * 32 + wv * 8 + (l >> 3);
    gB[s] = w2t + ((size_t)e * D_DIM + nt * 128 + n) * F_DIM + colg * 8;
  }
  f32x4 acc[2][2];
#pragma unroll
  for (int i = 0; i < 2; ++i)
#pragma unroll
    for (int j = 0; j < 2; ++j) acc[i][j] = (f32x4){0.f, 0.f, 0.f, 0.f};

  for (int ks = 0; ks < F_DIM / 64; ++ks) {
    __syncthreads();
    gld16(gA + ks * 64, sA + wv * 512);
#pragma unroll
    for (int s = 0; s < 4; ++s)
      gld16(gB[s] + ks * 64, sB + s * 2048 + wv * 512);
    __syncthreads();
#pragma unroll
    for (int kk = 0; kk < 2; ++kk) {
      int ko = kk * 32 + (l >> 4) * 8;
      short8 a[2], b[2];
      a[0] = *(const short8*)(sA + (l & 15) * 64 + ko);
      a[1] = *(const short8*)(sA + (16 + (l & 15)) * 64 + ko);
      b[0] = *(const short8*)(sB + (wv * 32 + (l & 15)) * 64 + ko);
      b[1] = *(const short8*)(sB + (wv * 32 + 16 + (l & 15)) * 64 + ko);
      acc[0][0] = __builtin_amdgcn_mfma_f32_16x16x32_bf16(a[0], b[0], acc[0][0], 0, 0, 0);
      acc[0][1] = __builtin_amdgcn_mfma_f32_16x16x32_bf16(a[0], b[1], acc[0][1], 0, 0, 0);
      acc[1][0] = __builtin_amdgcn_mfma_f32_16x16x32_bf16(a[1], b[0], acc[1][0], 0, 0, 0);
      acc[1][1] = __builtin_amdgcn_mfma_f32_16x16x32_bf16(a[1], b[1], acc[1][1], 0, 0, 0);
    }
  }
  int cloc = l & 15, rb = (l >> 4) * 4;
#pragma unroll
  for (int i = 0; i < 2; ++i)
#pragma unroll
    for (int j = 0; j < 2; ++j)
#pragma unroll
      for (int r = 0; r < 4; ++r) {
        int rl = mt * 32 + i * 16 + rb + r;
        if (rl < cnt) {
          int tok = list[base + rl];
          out[(size_t)tok * D_DIM + nt * 128 + wv * 32 + j * 16 + cloc] = wbuf[tok] * acc[i][j][r];
        }
      }
}

// ---------------- launch ----------------
extern "C" void kernel_launch(void* const* d_in, const int* in_sizes, int n_in,
                              void* d_out, int out_size, void* d_ws, size_t ws_size,
                              hipStream_t stream) {
  const float* x  = (const float*)d_in[0];
  const float* Wg = (const float*)d_in[1];
  const float* W1 = (const float*)d_in[2];
  const float* W2 = (const float*)d_in[3];
  const float* W3 = (const float*)d_in[4];
  float* out = (float*)d_out;
  char* ws = (char*)d_ws;

  int*            jbuf  = (int*)(ws + 0);            // int[2048]
  float*          wbuf  = (float*)(ws + 8192);       // float[2048]
  int*            cntp  = (int*)(ws + 16384);        // int[8]
  int*            basep = (int*)(ws + 16448);        // int[8]
  int*            list  = (int*)(ws + 16640);        // int[2048]
  unsigned short* xb    = (unsigned short*)(ws + 32768);                 // bf16 [2048][512]
  unsigned short* w1t   = (unsigned short*)(ws + 32768 + 2097152);       // bf16 [8][2048][512]
  unsigned short* w3t   = (unsigned short*)(ws + 32768 + 2097152 + 16777216);
  unsigned short* w2t   = (unsigned short*)(ws + 32768 + 2097152 + 2 * 16777216); // bf16 [8][512][2048]
  unsigned short* hbuf  = (unsigned short*)(ws + 32768 + 2097152 + 3 * 16777216); // bf16 [2048][2048]

  k_route<<<dim3(8), dim3(256), 0, stream>>>(x, Wg, jbuf, wbuf);
  k_bucket<<<dim3(1), dim3(256), 0, stream>>>(jbuf, cntp, basep, list);
  k_cvt_x<<<dim3(1024), dim3(256), 0, stream>>>(x, xb);
  k_tr<<<dim3(64, 16, 8), dim3(256), 0, stream>>>(W1, w1t, 512, 2048);
  k_tr<<<dim3(64, 16, 8), dim3(256), 0, stream>>>(W3, w3t, 512, 2048);
  k_tr<<<dim3(16, 64, 8), dim3(256), 0, stream>>>(W2, w2t, 2048, 512);
  k_ffn1<<<dim3(16, 16, 8), dim3(256), 0, stream>>>(xb, w1t, w3t, cntp, basep, list, hbuf);
  k_ffn2<<<dim3(64, 4, 8), dim3(256), 0, stream>>>(hbuf, w2t, cntp, basep, list, wbuf, out);
}

// Round 2
// 247.487 us; speedup vs baseline: 1.0482x; 1.0482x over previous
//
#include <hip/hip_runtime.h>
#include <hip/hip_bf16.h>
#include <math.h>

typedef __attribute__((ext_vector_type(8))) short short8;
typedef __attribute__((ext_vector_type(4))) float f32x4;

#define T_TOK 2048
#define D_DIM 512
#define F_DIM 2048
#define E_NUM 8

__device__ __forceinline__ unsigned short f2bf(float f) {
  union { float f; unsigned u; } c; c.f = f;
  unsigned u = c.u;
  return (unsigned short)((u + 0x7fffu + ((u >> 16) & 1u)) >> 16);
}

__device__ __forceinline__ void gld16(const void* g, void* l) {
  __builtin_amdgcn_global_load_lds((const __attribute__((address_space(1))) int*)g,
                                   (__attribute__((address_space(3))) int*)l, 16, 0, 0);
}

// ---------------- routing: logits + top-2 + weight ----------------
__global__ __launch_bounds__(256) void k_route(const float* __restrict__ x,
                                               const float* __restrict__ Wg,
                                               int* __restrict__ jbuf,
                                               float* __restrict__ wbuf) {
  int t = blockIdx.x * 256 + threadIdx.x;
  const float4* xr = (const float4*)(x + (size_t)t * D_DIM);
  float acc[8];
#pragma unroll
  for (int e = 0; e < 8; ++e) acc[e] = 0.f;
  for (int d4 = 0; d4 < D_DIM / 4; ++d4) {
    float4 xv = xr[d4];
    const float* xs = (const float*)&xv;
#pragma unroll
    for (int q = 0; q < 4; ++q) {
      const float4* wr = (const float4*)(Wg + (size_t)(d4 * 4 + q) * 8);
      float4 w0 = wr[0], w1 = wr[1];
      acc[0] += xs[q] * w0.x; acc[1] += xs[q] * w0.y;
      acc[2] += xs[q] * w0.z; acc[3] += xs[q] * w0.w;
      acc[4] += xs[q] * w1.x; acc[5] += xs[q] * w1.y;
      acc[6] += xs[q] * w1.z; acc[7] += xs[q] * w1.w;
    }
  }
  float l0 = -1e30f, l1 = -1e30f; int i0 = 0, i1 = 0;
#pragma unroll
  for (int e = 0; e < 8; ++e) {
    float l = acc[e];
    if (l > l0) { l1 = l0; i1 = i0; l0 = l; i0 = e; }
    else if (l > l1) { l1 = l; i1 = e; }
  }
  int j; float w;
  if (i0 > i1) { j = i0; w = 1.f / (1.f + expf(l1 - l0)); }
  else         { j = i1; w = 1.f / (1.f + expf(l0 - l1)); }
  jbuf[t] = j; wbuf[t] = w;
}

// ---------------- bucket: counts, bases, compact token lists ----------------
__global__ __launch_bounds__(256) void k_bucket(const int* __restrict__ jbuf,
                                                int* __restrict__ cntp,
                                                int* __restrict__ basep,
                                                int* __restrict__ list) {
  __shared__ int scnt[8], scur[8];
  int tid = threadIdx.x;
  if (tid < 8) scnt[tid] = 0;
  __syncthreads();
  for (int t = tid; t < T_TOK; t += 256) atomicAdd(&scnt[jbuf[t]], 1);
  __syncthreads();
  if (tid == 0) {
    int run = 0;
    for (int e = 0; e < 8; ++e) {
      scur[e] = run;
      cntp[e] = scnt[e]; basep[e] = run;
      run += scnt[e];
    }
  }
  __syncthreads();
  for (int t = tid; t < T_TOK; t += 256) {
    int j = jbuf[t];
    int p = atomicAdd(&scur[j], 1);
    list[p] = t;
  }
}

// ---------------- convert x -> bf16 ----------------
__global__ __launch_bounds__(256) void k_cvt_x(const float* __restrict__ x,
                                               unsigned short* __restrict__ xb) {
  int i = (blockIdx.x * 256 + threadIdx.x) * 4;
  float4 v = *(const float4*)(x + i);
  ushort4 o;
  o.x = f2bf(v.x); o.y = f2bf(v.y); o.z = f2bf(v.z); o.w = f2bf(v.w);
  *(ushort4*)(xb + i) = o;
}

// ------- transpose f32 [Z][R][C] -> bf16 [Z][C][R], 64x64 tiles, vector I/O -------
__global__ __launch_bounds__(256) void k_tr2(const float* __restrict__ inA,
                                             const float* __restrict__ inB,
                                             unsigned short* __restrict__ outA,
                                             unsigned short* __restrict__ outB,
                                             int R, int C) {
  __shared__ float tile[64][65];
  int z = blockIdx.z;
  const float* in; unsigned short* out;
  if (z < 8) { in = inA + (size_t)z * R * C;       out = outA + (size_t)z * R * C; }
  else       { in = inB + (size_t)(z - 8) * R * C; out = outB + (size_t)(z - 8) * R * C; }
  int c0 = blockIdx.x * 64, r0 = blockIdx.y * 64;
  int tx = threadIdx.x & 15, ty = threadIdx.x >> 4;
#pragma unroll
  for (int k = 0; k < 4; ++k) {
    float4 v = *(const float4*)(in + (size_t)(r0 + ty + 16 * k) * C + c0 + tx * 4);
    tile[ty + 16 * k][tx * 4 + 0] = v.x;
    tile[ty + 16 * k][tx * 4 + 1] = v.y;
    tile[ty + 16 * k][tx * 4 + 2] = v.z;
    tile[ty + 16 * k][tx * 4 + 3] = v.w;
  }
  __syncthreads();
#pragma unroll
  for (int k = 0; k < 4; ++k) {
    int orow = c0 + ty + 16 * k;
    ushort4 o;
    o.x = f2bf(tile[tx * 4 + 0][ty + 16 * k]);
    o.y = f2bf(tile[tx * 4 + 1][ty + 16 * k]);
    o.z = f2bf(tile[tx * 4 + 2][ty + 16 * k]);
    o.w = f2bf(tile[tx * 4 + 3][ty + 16 * k]);
    *(ushort4*)(out + (size_t)orow * R + r0 + tx * 4) = o;
  }
}

// ------- pass 1: u=X@W1, v=X@W3, h=silu(u)*v; BM=128 BN=64 BK=64, dbuf 2-phase -------
__global__ __launch_bounds__(256, 2) void k_ffn1(const unsigned short* __restrict__ xb,
                                                 const unsigned short* __restrict__ w1t,
                                                 const unsigned short* __restrict__ w3t,
                                                 const int* __restrict__ cntp,
                                                 const int* __restrict__ basep,
                                                 const int* __restrict__ list,
                                                 unsigned short* __restrict__ hbuf) {
  int e = blockIdx.z, mt = blockIdx.x, nt = blockIdx.y;
  int cnt = cntp[e];
  if (mt * 128 >= cnt) return;
  int base = basep[e];
  __shared__ unsigned short sA[2 * 8192], sB1[2 * 4096], sB3[2 * 4096];
  int tid = threadIdx.x, wv = tid >> 6, l = tid & 63;
  int wr = wv >> 1, wc = wv & 1;
  int colg = (l & 7) * 8;
  const unsigned short *gA[4], *gB1[2], *gB3[2];
#pragma unroll
  for (int s = 0; s < 4; ++s) {
    int rr = mt * 128 + s * 32 + wv * 8 + (l >> 3);
    if (rr >= cnt) rr = cnt - 1;
    gA[s] = xb + (size_t)list[base + rr] * D_DIM + colg;
  }
#pragma unroll
  for (int s = 0; s < 2; ++s) {
    int f = nt * 64 + s * 32 + wv * 8 + (l >> 3);
    gB1[s] = w1t + ((size_t)e * F_DIM + f) * D_DIM + colg;
    gB3[s] = w3t + ((size_t)e * F_DIM + f) * D_DIM + colg;
  }
  f32x4 au[4][2], av[4][2];
#pragma unroll
  for (int i = 0; i < 4; ++i)
#pragma unroll
    for (int j = 0; j < 2; ++j) {
      au[i][j] = (f32x4){0.f, 0.f, 0.f, 0.f};
      av[i][j] = (f32x4){0.f, 0.f, 0.f, 0.f};
    }

  auto stage = [&](int buf, int ks) {
#pragma unroll
    for (int s = 0; s < 4; ++s)
      gld16(gA[s] + ks * 64, sA + buf * 8192 + s * 2048 + wv * 512);
#pragma unroll
    for (int s = 0; s < 2; ++s) {
      gld16(gB1[s] + ks * 64, sB1 + buf * 4096 + s * 2048 + wv * 512);
      gld16(gB3[s] + ks * 64, sB3 + buf * 4096 + s * 2048 + wv * 512);
    }
  };

  stage(0, 0);
  __syncthreads();
  int cur = 0;
  for (int ks = 0; ks < 8; ++ks) {
    if (ks < 7) stage(cur ^ 1, ks + 1);   // prefetch next K-step (overlaps compute)
#pragma unroll
    for (int kk = 0; kk < 2; ++kk) {
      int ko = kk * 32 + (l >> 4) * 8;
      short8 a[4], b1[2], b3[2];
#pragma unroll
      for (int i = 0; i < 4; ++i)
        a[i] = *(const short8*)(sA + cur * 8192 + (wr * 64 + i * 16 + (l & 15)) * 64 + ko);
#pragma unroll
      for (int j = 0; j < 2; ++j) {
        b1[j] = *(const short8*)(sB1 + cur * 4096 + (wc * 32 + j * 16 + (l & 15)) * 64 + ko);
        b3[j] = *(const short8*)(sB3 + cur * 4096 + (wc * 32 + j * 16 + (l & 15)) * 64 + ko);
      }
#pragma unroll
      for (int i = 0; i < 4; ++i)
#pragma unroll
        for (int j = 0; j < 2; ++j) {
          au[i][j] = __builtin_amdgcn_mfma_f32_16x16x32_bf16(a[i], b1[j], au[i][j], 0, 0, 0);
          av[i][j] = __builtin_amdgcn_mfma_f32_16x16x32_bf16(a[i], b3[j], av[i][j], 0, 0, 0);
        }
    }
    __syncthreads();   // drains prefetch (vmcnt) + protects buf[cur] reuse
    cur ^= 1;
  }
  int cloc = l & 15, rb = (l >> 4) * 4;
#pragma unroll
  for (int i = 0; i < 4; ++i)
#pragma unroll
    for (int j = 0; j < 2; ++j) {
      int col = nt * 64 + wc * 32 + j * 16 + cloc;
#pragma unroll
      for (int r = 0; r < 4; ++r) {
        int rl = mt * 128 + wr * 64 + i * 16 + rb + r;
        if (rl < cnt) {
          float uu = au[i][j][r], vv = av[i][j][r];
          float hh = (uu / (1.f + expf(-uu))) * vv;
          hbuf[(size_t)(base + rl) * F_DIM + col] = f2bf(hh);
        }
      }
    }
}

// ------- pass 2: y = h @ W2, out[tok] = w*y; BM=32 BN=128 BK=128, dbuf 2-phase -------
__global__ __launch_bounds__(256, 2) void k_ffn2(const unsigned short* __restrict__ hbuf,
                                                 const unsigned short* __restrict__ w2t,
                                                 const int* __restrict__ cntp,
                                                 const int* __restrict__ basep,
                                                 const int* __restrict__ list,
                                                 const float* __restrict__ wbuf,
                                                 float* __restrict__ out) {
  int e = blockIdx.z, mt = blockIdx.x, nt = blockIdx.y;
  int cnt = cntp[e];
  if (mt * 32 >= cnt) return;
  int base = basep[e];
  __shared__ unsigned short sA[2 * 4096], sB[2 * 16384];
  int tid = threadIdx.x, wv = tid >> 6, l = tid & 63;
  int colg = (l & 15) * 8;
  const unsigned short *gA[2], *gB[8];
#pragma unroll
  for (int s = 0; s < 2; ++s) {
    int rr = mt * 32 + s * 16 + wv * 4 + (l >> 4);
    if (rr >= cnt) rr = cnt - 1;
    gA[s] = hbuf + (size_t)(base + rr) * F_DIM + colg;
  }
#pragma unroll
  for (int s = 0; s < 8; ++s) {
    int n = nt * 128 + s * 16 + wv * 4 + (l >> 4);
    gB[s] = w2t + ((size_t)e * D_DIM + n) * F_DIM + colg;
  }
  f32x4 acc[2][2];
#pragma unroll
  for (int i = 0; i < 2; ++i)
#pragma unroll
    for (int j = 0; j < 2; ++j) acc[i][j] = (f32x4){0.f, 0.f, 0.f, 0.f};

  auto stage = [&](int buf, int ks) {
#pragma unroll
    for (int s = 0; s < 2; ++s)
      gld16(gA[s] + ks * 128, sA + buf * 4096 + s * 2048 + wv * 512);
#pragma unroll
    for (int s = 0; s < 8; ++s)
      gld16(gB[s] + ks * 128, sB + buf * 16384 + s * 2048 + wv * 512);
  };

  stage(0, 0);
  __syncthreads();
  int cur = 0;
  for (int ks = 0; ks < 16; ++ks) {
    if (ks < 15) stage(cur ^ 1, ks + 1);
#pragma unroll
    for (int kk = 0; kk < 4; ++kk) {
      int ko = kk * 32 + (l >> 4) * 8;
      short8 a[2], b[2];
#pragma unroll
      for (int i = 0; i < 2; ++i)
        a[i] = *(const short8*)(sA + cur * 4096 + (i * 16 + (l & 15)) * 128 + ko);
#pragma unroll
      for (int j = 0; j < 2; ++j)
        b[j] = *(const short8*)(sB + cur * 16384 + (wv * 32 + j * 16 + (l & 15)) * 128 + ko);
      acc[0][0] = __builtin_amdgcn_mfma_f32_16x16x32_bf16(a[0], b[0], acc[0][0], 0, 0, 0);
      acc[0][1] = __builtin_amdgcn_mfma_f32_16x16x32_bf16(a[0], b[1], acc[0][1], 0, 0, 0);
      acc[1][0] = __builtin_amdgcn_mfma_f32_16x16x32_bf16(a[1], b[0], acc[1][0], 0, 0, 0);
      acc[1][1] = __builtin_amdgcn_mfma_f32_16x16x32_bf16(a[1], b[1], acc[1][1], 0, 0, 0);
    }
    __syncthreads();
    cur ^= 1;
  }
  int cloc = l & 15, rb = (l >> 4) * 4;
#pragma unroll
  for (int i = 0; i < 2; ++i)
#pragma unroll
    for (int j = 0; j < 2; ++j)
#pragma unroll
      for (int r = 0; r < 4; ++r) {
        int rl = mt * 32 + i * 16 + rb + r;
        if (rl < cnt) {
          int tok = list[base + rl];
          out[(size_t)tok * D_DIM + nt * 128 + wv * 32 + j * 16 + cloc] = wbuf[tok] * acc[i][j][r];
        }
      }
}

// ---------------- launch ----------------
extern "C" void kernel_launch(void* const* d_in, const int* in_sizes, int n_in,
                              void* d_out, int out_size, void* d_ws, size_t ws_size,
                              hipStream_t stream) {
  const float* x  = (const float*)d_in[0];
  const float* Wg = (const float*)d_in[1];
  const float* W1 = (const float*)d_in[2];
  const float* W2 = (const float*)d_in[3];
  const float* W3 = (const float*)d_in[4];
  float* out = (float*)d_out;
  char* ws = (char*)d_ws;

  int*            jbuf  = (int*)(ws + 0);
  float*          wbuf  = (float*)(ws + 8192);
  int*            cntp  = (int*)(ws + 16384);
  int*            basep = (int*)(ws + 16448);
  int*            list  = (int*)(ws + 16640);
  unsigned short* xb    = (unsigned short*)(ws + 32768);                          // bf16 [2048][512]
  unsigned short* w1t   = (unsigned short*)(ws + 32768 + 2097152);                // bf16 [8][2048][512]
  unsigned short* w3t   = (unsigned short*)(ws + 32768 + 2097152 + 16777216);
  unsigned short* w2t   = (unsigned short*)(ws + 32768 + 2097152 + 2 * 16777216); // bf16 [8][512][2048]
  unsigned short* hbuf  = (unsigned short*)(ws + 32768 + 2097152 + 3 * 16777216); // bf16 [2048][2048]

  k_route<<<dim3(8), dim3(256), 0, stream>>>(x, Wg, jbuf, wbuf);
  k_bucket<<<dim3(1), dim3(256), 0, stream>>>(jbuf, cntp, basep, list);
  k_cvt_x<<<dim3(1024), dim3(256), 0, stream>>>(x, xb);
  k_tr2<<<dim3(32, 8, 16), dim3(256), 0, stream>>>(W1, W3, w1t, w3t, 512, 2048);
  k_tr2<<<dim3(8, 32, 8), dim3(256), 0, stream>>>(W2, W2, w2t, w2t, 2048, 512);
  k_ffn1<<<dim3(16, 32, 8), dim3(256), 0, stream>>>(xb, w1t, w3t, cntp, basep, list, hbuf);
  k_ffn2<<<dim3(64, 4, 8), dim3(256), 0, stream>>>(hbuf, w2t, cntp, basep, list, wbuf, out);
}

// Round 3
// 128.220 us; speedup vs baseline: 2.0232x; 1.9302x over previous
//
#include <hip/hip_runtime.h>
#include <hip/hip_bf16.h>
#include <math.h>

typedef __attribute__((ext_vector_type(8))) short short8;
typedef __attribute__((ext_vector_type(4))) float f32x4;

#define T_TOK 2048
#define D_DIM 512
#define F_DIM 2048
#define E_NUM 8
#define MAXT1 40   // >= sum_e ceil(cnt_e/64) <= 32+7
#define MAXT2 72   // >= sum_e ceil(cnt_e/32) <= 64+7

__device__ __forceinline__ unsigned short f2bf(float f) {
  union { float f; unsigned u; } c; c.f = f;
  unsigned u = c.u;
  return (unsigned short)((u + 0x7fffu + ((u >> 16) & 1u)) >> 16);
}

__device__ __forceinline__ void gld16(const void* g, void* l) {
  __builtin_amdgcn_global_load_lds((const __attribute__((address_space(1))) int*)g,
                                   (__attribute__((address_space(3))) int*)l, 16, 0, 0);
}

// ---- routing: logits (8-way K-split) + top-2 + weight; also converts x->bf16 ----
__global__ __launch_bounds__(256) void k_route(const float* __restrict__ x,
                                               const float* __restrict__ Wg,
                                               int* __restrict__ jbuf,
                                               float* __restrict__ wbuf,
                                               unsigned short* __restrict__ xb) {
  int gid = blockIdx.x * 256 + threadIdx.x;
  int t = gid >> 3, seg = gid & 7;
  const float* xp = x + (size_t)t * D_DIM + seg * 64;
  unsigned short* xo = xb + (size_t)t * D_DIM + seg * 64;
  float acc[8];
#pragma unroll
  for (int e = 0; e < 8; ++e) acc[e] = 0.f;
#pragma unroll
  for (int i = 0; i < 16; ++i) {
    float4 v = *(const float4*)(xp + i * 4);
    ushort4 o;
    o.x = f2bf(v.x); o.y = f2bf(v.y); o.z = f2bf(v.z); o.w = f2bf(v.w);
    *(ushort4*)(xo + i * 4) = o;
    const float* xs = (const float*)&v;
#pragma unroll
    for (int q = 0; q < 4; ++q) {
      int d = seg * 64 + i * 4 + q;
      const float4* wr = (const float4*)(Wg + (size_t)d * 8);
      float4 w0 = wr[0], w1 = wr[1];
      acc[0] += xs[q] * w0.x; acc[1] += xs[q] * w0.y;
      acc[2] += xs[q] * w0.z; acc[3] += xs[q] * w0.w;
      acc[4] += xs[q] * w1.x; acc[5] += xs[q] * w1.y;
      acc[6] += xs[q] * w1.z; acc[7] += xs[q] * w1.w;
    }
  }
#pragma unroll
  for (int off = 1; off < 8; off <<= 1)
#pragma unroll
    for (int e = 0; e < 8; ++e) acc[e] += __shfl_xor(acc[e], off);
  if (seg == 0) {
    float l0 = -1e30f, l1 = -1e30f; int i0 = 0, i1 = 0;
#pragma unroll
    for (int e = 0; e < 8; ++e) {
      float l = acc[e];
      if (l > l0) { l1 = l0; i1 = i0; l0 = l; i0 = e; }
      else if (l > l1) { l1 = l; i1 = e; }
    }
    int j; float w;
    if (i0 > i1) { j = i0; w = 1.f / (1.f + expf(l1 - l0)); }
    else         { j = i1; w = 1.f / (1.f + expf(l0 - l1)); }
    jbuf[t] = j; wbuf[t] = w;
  }
}

// ---- bucket: counts, bases, compact token lists, compact TILE lists ----
__global__ __launch_bounds__(256) void k_bucket(const int* __restrict__ jbuf,
                                                int* __restrict__ cntp,
                                                int* __restrict__ basep,
                                                int* __restrict__ list,
                                                int* __restrict__ tl1,
                                                int* __restrict__ tl2,
                                                int* __restrict__ ntl) {
  __shared__ int scnt[8], scur[8];
  int tid = threadIdx.x;
  if (tid < 8) scnt[tid] = 0;
  __syncthreads();
  for (int t = tid; t < T_TOK; t += 256) atomicAdd(&scnt[jbuf[t]], 1);
  __syncthreads();
  if (tid == 0) {
    int run = 0;
    for (int e = 0; e < 8; ++e) {
      cntp[e] = scnt[e]; basep[e] = run; scur[e] = run;
      run += scnt[e];
    }
    int n1 = 0, bb = 0;
    for (int e = 0; e < 8; ++e) {
      for (int m = 0; m < scnt[e]; m += 64) tl1[n1++] = (e << 16) | (bb + m);
      bb += scnt[e];
    }
    int n2 = 0; bb = 0;
    for (int e = 0; e < 8; ++e) {
      for (int m = 0; m < scnt[e]; m += 32) tl2[n2++] = (e << 16) | (bb + m);
      bb += scnt[e];
    }
    ntl[0] = n1; ntl[1] = n2;
  }
  __syncthreads();
  for (int t = tid; t < T_TOK; t += 256) {
    int j = jbuf[t];
    int p = atomicAdd(&scur[j], 1);
    list[p] = t;
  }
}

// ---- transpose f32 [Z][R][C] -> bf16 [Z][C][R], 64x64 tiles, vector I/O ----
__global__ __launch_bounds__(256) void k_tr2(const float* __restrict__ inA,
                                             const float* __restrict__ inB,
                                             unsigned short* __restrict__ outA,
                                             unsigned short* __restrict__ outB,
                                             int R, int C) {
  __shared__ float tile[64][65];
  int z = blockIdx.z;
  const float* in; unsigned short* out;
  if (z < 8) { in = inA + (size_t)z * R * C;       out = outA + (size_t)z * R * C; }
  else       { in = inB + (size_t)(z - 8) * R * C; out = outB + (size_t)(z - 8) * R * C; }
  int c0 = blockIdx.x * 64, r0 = blockIdx.y * 64;
  int tx = threadIdx.x & 15, ty = threadIdx.x >> 4;
#pragma unroll
  for (int k = 0; k < 4; ++k) {
    float4 v = *(const float4*)(in + (size_t)(r0 + ty + 16 * k) * C + c0 + tx * 4);
    tile[ty + 16 * k][tx * 4 + 0] = v.x;
    tile[ty + 16 * k][tx * 4 + 1] = v.y;
    tile[ty + 16 * k][tx * 4 + 2] = v.z;
    tile[ty + 16 * k][tx * 4 + 3] = v.w;
  }
  __syncthreads();
#pragma unroll
  for (int k = 0; k < 4; ++k) {
    int orow = c0 + ty + 16 * k;
    ushort4 o;
    o.x = f2bf(tile[tx * 4 + 0][ty + 16 * k]);
    o.y = f2bf(tile[tx * 4 + 1][ty + 16 * k]);
    o.z = f2bf(tile[tx * 4 + 2][ty + 16 * k]);
    o.w = f2bf(tile[tx * 4 + 3][ty + 16 * k]);
    *(ushort4*)(out + (size_t)orow * R + r0 + tx * 4) = o;
  }
}

// ---- pass 1: u=X@W1, v=X@W3, h=silu(u)*v; BM=64 BN=64 BK=64, dbuf, compact tiles ----
__global__ __launch_bounds__(256, 3) void k_ffn1(const unsigned short* __restrict__ xb,
                                                 const unsigned short* __restrict__ w1t,
                                                 const unsigned short* __restrict__ w3t,
                                                 const int* __restrict__ cntp,
                                                 const int* __restrict__ basep,
                                                 const int* __restrict__ list,
                                                 const int* __restrict__ tl1,
                                                 const int* __restrict__ ntl,
                                                 unsigned short* __restrict__ hbuf) {
  if ((int)blockIdx.x >= ntl[0]) return;
  int pk = tl1[blockIdx.x];
  int e = pk >> 16, g0 = pk & 0xffff;
  int lim = basep[e] + cntp[e];
  int nt = blockIdx.y;
  __shared__ unsigned short sA[2 * 4096], sB1[2 * 4096], sB3[2 * 4096];
  int tid = threadIdx.x, wv = tid >> 6, l = tid & 63;
  int wr = wv >> 1, wc = wv & 1;
  int colg = (l & 7) * 8;
  const unsigned short *gA[2], *gB1[2], *gB3[2];
#pragma unroll
  for (int s = 0; s < 2; ++s) {
    int r = wv * 16 + s * 8 + (l >> 3);
    int gr = g0 + r; if (gr >= lim) gr = lim - 1;
    gA[s] = xb + (size_t)list[gr] * D_DIM + colg;
    int f = nt * 64 + r;
    gB1[s] = w1t + ((size_t)e * F_DIM + f) * D_DIM + colg;
    gB3[s] = w3t + ((size_t)e * F_DIM + f) * D_DIM + colg;
  }
  f32x4 au[2][2], av[2][2];
#pragma unroll
  for (int i = 0; i < 2; ++i)
#pragma unroll
    for (int j = 0; j < 2; ++j) {
      au[i][j] = (f32x4){0.f, 0.f, 0.f, 0.f};
      av[i][j] = (f32x4){0.f, 0.f, 0.f, 0.f};
    }

  auto stage = [&](int buf, int ks) {
#pragma unroll
    for (int s = 0; s < 2; ++s) {
      int dst = buf * 4096 + (wv * 16 + s * 8) * 64;
      gld16(gA[s] + ks * 64, sA + dst);
      gld16(gB1[s] + ks * 64, sB1 + dst);
      gld16(gB3[s] + ks * 64, sB3 + dst);
    }
  };

  stage(0, 0);
  __syncthreads();
  int cur = 0;
  for (int ks = 0; ks < 8; ++ks) {
    if (ks < 7) stage(cur ^ 1, ks + 1);
#pragma unroll
    for (int kk = 0; kk < 2; ++kk) {
      int ko = kk * 32 + (l >> 4) * 8;
      short8 a[2], b1[2], b3[2];
#pragma unroll
      for (int i = 0; i < 2; ++i)
        a[i] = *(const short8*)(sA + cur * 4096 + (wr * 32 + i * 16 + (l & 15)) * 64 + ko);
#pragma unroll
      for (int j = 0; j < 2; ++j) {
        b1[j] = *(const short8*)(sB1 + cur * 4096 + (wc * 32 + j * 16 + (l & 15)) * 64 + ko);
        b3[j] = *(const short8*)(sB3 + cur * 4096 + (wc * 32 + j * 16 + (l & 15)) * 64 + ko);
      }
#pragma unroll
      for (int i = 0; i < 2; ++i)
#pragma unroll
        for (int j = 0; j < 2; ++j) {
          au[i][j] = __builtin_amdgcn_mfma_f32_16x16x32_bf16(a[i], b1[j], au[i][j], 0, 0, 0);
          av[i][j] = __builtin_amdgcn_mfma_f32_16x16x32_bf16(a[i], b3[j], av[i][j], 0, 0, 0);
        }
    }
    __syncthreads();
    cur ^= 1;
  }
  int cloc = l & 15, rb = (l >> 4) * 4;
#pragma unroll
  for (int i = 0; i < 2; ++i)
#pragma unroll
    for (int j = 0; j < 2; ++j) {
      int col = nt * 64 + wc * 32 + j * 16 + cloc;
#pragma unroll
      for (int r = 0; r < 4; ++r) {
        int gr = g0 + wr * 32 + i * 16 + rb + r;
        if (gr < lim) {
          float uu = au[i][j][r], vv = av[i][j][r];
          float hh = (uu / (1.f + expf(-uu))) * vv;
          hbuf[(size_t)gr * F_DIM + col] = f2bf(hh);
        }
      }
    }
}

// ---- pass 2: y = h @ W2, out[tok] = w*y; BM=32 BN=64 BK=128, dbuf, compact tiles ----
__global__ __launch_bounds__(256, 3) void k_ffn2(const unsigned short* __restrict__ hbuf,
                                                 const unsigned short* __restrict__ w2t,
                                                 const int* __restrict__ cntp,
                                                 const int* __restrict__ basep,
                                                 const int* __restrict__ list,
                                                 const int* __restrict__ tl2,
                                                 const int* __restrict__ ntl,
                                                 const float* __restrict__ wbuf,
                                                 float* __restrict__ out) {
  if ((int)blockIdx.x >= ntl[1]) return;
  int pk = tl2[blockIdx.x];
  int e = pk >> 16, g0 = pk & 0xffff;
  int lim = basep[e] + cntp[e];
  int nt = blockIdx.y;
  __shared__ unsigned short sA[2 * 4096], sB[2 * 8192];
  int tid = threadIdx.x, wv = tid >> 6, l = tid & 63;
  int wr = wv >> 1, wc = wv & 1;
  int colg = (l & 15) * 8;
  const unsigned short *gA[2], *gB[4];
#pragma unroll
  for (int s = 0; s < 2; ++s) {
    int gr = g0 + wv * 8 + s * 4 + (l >> 4);
    if (gr > T_TOK - 1) gr = T_TOK - 1;          // clamp: stay inside hbuf
    gA[s] = hbuf + (size_t)gr * F_DIM + colg;
  }
#pragma unroll
  for (int s = 0; s < 4; ++s) {
    int dd = nt * 64 + wv * 16 + s * 4 + (l >> 4);
    gB[s] = w2t + ((size_t)e * D_DIM + dd) * F_DIM + colg;
  }
  f32x4 acc[2];
  acc[0] = (f32x4){0.f, 0.f, 0.f, 0.f};
  acc[1] = (f32x4){0.f, 0.f, 0.f, 0.f};

  auto stage = [&](int buf, int ks) {
#pragma unroll
    for (int s = 0; s < 2; ++s)
      gld16(gA[s] + ks * 128, sA + buf * 4096 + (wv * 8 + s * 4) * 128);
#pragma unroll
    for (int s = 0; s < 4; ++s)
      gld16(gB[s] + ks * 128, sB + buf * 8192 + (wv * 16 + s * 4) * 128);
  };

  stage(0, 0);
  __syncthreads();
  int cur = 0;
  for (int ks = 0; ks < 16; ++ks) {
    if (ks < 15) stage(cur ^ 1, ks + 1);
#pragma unroll
    for (int kk = 0; kk < 4; ++kk) {
      int ko = kk * 32 + (l >> 4) * 8;
      short8 a  = *(const short8*)(sA + cur * 4096 + (wr * 16 + (l & 15)) * 128 + ko);
      short8 b0 = *(const short8*)(sB + cur * 8192 + (wc * 32 + (l & 15)) * 128 + ko);
      short8 b1 = *(const short8*)(sB + cur * 8192 + (wc * 32 + 16 + (l & 15)) * 128 + ko);
      acc[0] = __builtin_amdgcn_mfma_f32_16x16x32_bf16(a, b0, acc[0], 0, 0, 0);
      acc[1] = __builtin_amdgcn_mfma_f32_16x16x32_bf16(a, b1, acc[1], 0, 0, 0);
    }
    __syncthreads();
    cur ^= 1;
  }
  int cloc = l & 15, rb = (l >> 4) * 4;
#pragma unroll
  for (int j = 0; j < 2; ++j)
#pragma unroll
    for (int r = 0; r < 4; ++r) {
      int gr = g0 + wr * 16 + rb + r;
      if (gr < lim) {
        int tok = list[gr];
        out[(size_t)tok * D_DIM + nt * 64 + wc * 32 + j * 16 + cloc] = wbuf[tok] * acc[j][r];
      }
    }
}

// ---------------- launch ----------------
extern "C" void kernel_launch(void* const* d_in, const int* in_sizes, int n_in,
                              void* d_out, int out_size, void* d_ws, size_t ws_size,
                              hipStream_t stream) {
  const float* x  = (const float*)d_in[0];
  const float* Wg = (const float*)d_in[1];
  const float* W1 = (const float*)d_in[2];
  const float* W2 = (const float*)d_in[3];
  const float* W3 = (const float*)d_in[4];
  float* out = (float*)d_out;
  char* ws = (char*)d_ws;

  int*            jbuf  = (int*)(ws + 0);
  float*          wbuf  = (float*)(ws + 8192);
  int*            cntp  = (int*)(ws + 16384);
  int*            basep = (int*)(ws + 16448);
  int*            list  = (int*)(ws + 16640);      // int[2048] -> ends 24832
  int*            tl1   = (int*)(ws + 24832);      // int[40]
  int*            tl2   = (int*)(ws + 25088);      // int[72]
  int*            ntl   = (int*)(ws + 25600);      // int[2]
  unsigned short* xb    = (unsigned short*)(ws + 32768);                          // bf16 [2048][512]
  unsigned short* w1t   = (unsigned short*)(ws + 32768 + 2097152);                // bf16 [8][2048][512]
  unsigned short* w3t   = (unsigned short*)(ws + 32768 + 2097152 + 16777216);
  unsigned short* w2t   = (unsigned short*)(ws + 32768 + 2097152 + 2 * 16777216); // bf16 [8][512][2048]
  unsigned short* hbuf  = (unsigned short*)(ws + 32768 + 2097152 + 3 * 16777216); // bf16 [2048][2048]

  k_route<<<dim3(64), dim3(256), 0, stream>>>(x, Wg, jbuf, wbuf, xb);
  k_bucket<<<dim3(1), dim3(256), 0, stream>>>(jbuf, cntp, basep, list, tl1, tl2, ntl);
  k_tr2<<<dim3(32, 8, 16), dim3(256), 0, stream>>>(W1, W3, w1t, w3t, 512, 2048);
  k_tr2<<<dim3(8, 32, 8), dim3(256), 0, stream>>>(W2, W2, w2t, w2t, 2048, 512);
  k_ffn1<<<dim3(MAXT1, 32), dim3(256), 0, stream>>>(xb, w1t, w3t, cntp, basep, list, tl1, ntl, hbuf);
  k_ffn2<<<dim3(MAXT2, 8), dim3(256), 0, stream>>>(hbuf, w2t, cntp, basep, list, tl2, ntl, wbuf, out);
}

// Round 4
// 108.797 us; speedup vs baseline: 2.3844x; 1.1785x over previous
//
#include <hip/hip_runtime.h>
#include <hip/hip_bf16.h>
#include <math.h>

typedef __attribute__((ext_vector_type(8))) short short8;
typedef __attribute__((ext_vector_type(4))) float f32x4;

#define T_TOK 2048
#define D_DIM 512
#define F_DIM 2048
#define E_NUM 8
#define MAXT1 40   // >= sum_e ceil(cnt_e/64) <= 32+7

__device__ __forceinline__ unsigned short f2bf(float f) {
  union { float f; unsigned u; } c; c.f = f;
  unsigned u = c.u;
  return (unsigned short)((u + 0x7fffu + ((u >> 16) & 1u)) >> 16);
}

__device__ __forceinline__ void gld16(const void* g, void* l) {
  __builtin_amdgcn_global_load_lds((const __attribute__((address_space(1))) int*)g,
                                   (__attribute__((address_space(3))) int*)l, 16, 0, 0);
}

// ---- routing: logits (32-way K-split) + top-2 + weight; also converts x->bf16 ----
__global__ __launch_bounds__(256) void k_route(const float* __restrict__ x,
                                               const float* __restrict__ Wg,
                                               int* __restrict__ jbuf,
                                               float* __restrict__ wbuf,
                                               unsigned short* __restrict__ xb) {
  int gid = blockIdx.x * 256 + threadIdx.x;
  int t = gid >> 5, seg = gid & 31;
  const float* xp = x + (size_t)t * D_DIM + seg * 16;
  unsigned short* xo = xb + (size_t)t * D_DIM + seg * 16;
  float acc[8];
#pragma unroll
  for (int e = 0; e < 8; ++e) acc[e] = 0.f;
#pragma unroll
  for (int i = 0; i < 4; ++i) {
    float4 v = *(const float4*)(xp + i * 4);
    ushort4 o;
    o.x = f2bf(v.x); o.y = f2bf(v.y); o.z = f2bf(v.z); o.w = f2bf(v.w);
    *(ushort4*)(xo + i * 4) = o;
    const float* xs = (const float*)&v;
#pragma unroll
    for (int q = 0; q < 4; ++q) {
      int d = seg * 16 + i * 4 + q;
      const float4* wr = (const float4*)(Wg + (size_t)d * 8);
      float4 w0 = wr[0], w1 = wr[1];
      acc[0] += xs[q] * w0.x; acc[1] += xs[q] * w0.y;
      acc[2] += xs[q] * w0.z; acc[3] += xs[q] * w0.w;
      acc[4] += xs[q] * w1.x; acc[5] += xs[q] * w1.y;
      acc[6] += xs[q] * w1.z; acc[7] += xs[q] * w1.w;
    }
  }
#pragma unroll
  for (int off = 1; off < 32; off <<= 1)
#pragma unroll
    for (int e = 0; e < 8; ++e) acc[e] += __shfl_xor(acc[e], off);
  if (seg == 0) {
    float l0 = -1e30f, l1 = -1e30f; int i0 = 0, i1 = 0;
#pragma unroll
    for (int e = 0; e < 8; ++e) {
      float l = acc[e];
      if (l > l0) { l1 = l0; i1 = i0; l0 = l; i0 = e; }
      else if (l > l1) { l1 = l; i1 = e; }
    }
    int j; float w;
    if (i0 > i1) { j = i0; w = 1.f / (1.f + expf(l1 - l0)); }
    else         { j = i1; w = 1.f / (1.f + expf(l0 - l1)); }
    jbuf[t] = j; wbuf[t] = w;
  }
}

// ---- bucket: counts, bases, compact token list, compact tile list (BM=64) ----
__global__ __launch_bounds__(256) void k_bucket(const int* __restrict__ jbuf,
                                                int* __restrict__ cntp,
                                                int* __restrict__ basep,
                                                int* __restrict__ list,
                                                int* __restrict__ tl1,
                                                int* __restrict__ ntl) {
  __shared__ int scnt[8], scur[8];
  int tid = threadIdx.x;
  if (tid < 8) scnt[tid] = 0;
  __syncthreads();
  for (int t = tid; t < T_TOK; t += 256) atomicAdd(&scnt[jbuf[t]], 1);
  __syncthreads();
  if (tid == 0) {
    int run = 0;
    for (int e = 0; e < 8; ++e) {
      cntp[e] = scnt[e]; basep[e] = run; scur[e] = run;
      run += scnt[e];
    }
    int n1 = 0, bb = 0;
    for (int e = 0; e < 8; ++e) {
      for (int m = 0; m < scnt[e]; m += 64) tl1[n1++] = (e << 16) | (bb + m);
      bb += scnt[e];
    }
    ntl[0] = n1;
  }
  __syncthreads();
  for (int t = tid; t < T_TOK; t += 256) {
    int j = jbuf[t];
    int p = atomicAdd(&scur[j], 1);
    list[p] = t;
  }
}

// ---- weight reformat: [Z][K][N] f32 -> fragment-major bf16 [Z][N/16][K/32][64][8] ----
__global__ __launch_bounds__(256) void k_wfrag(const float* __restrict__ inA,
                                               const float* __restrict__ inB,
                                               unsigned short* __restrict__ outA,
                                               unsigned short* __restrict__ outB,
                                               int K, int N) {
  __shared__ float tile[64][65];
  int z = blockIdx.z;
  const float* in; unsigned short* out;
  size_t zsz = (size_t)(K / 32) * (N / 16) * 512;
  if (z < 8) { in = inA + (size_t)z * K * N;       out = outA + (size_t)z * zsz; }
  else       { in = inB + (size_t)(z - 8) * K * N; out = outB + (size_t)(z - 8) * zsz; }
  int n0 = blockIdx.x * 64, k0 = blockIdx.y * 64;
  int tid = threadIdx.x;
  int lr = tid >> 4, lc = tid & 15;
#pragma unroll
  for (int it = 0; it < 4; ++it) {
    int row = it * 16 + lr;
    float4 v = *(const float4*)(in + (size_t)(k0 + row) * N + n0 + lc * 4);
    tile[row][lc * 4 + 0] = v.x;
    tile[row][lc * 4 + 1] = v.y;
    tile[row][lc * 4 + 2] = v.z;
    tile[row][lc * 4 + 3] = v.w;
  }
  __syncthreads();
  int wv = tid >> 6, l = tid & 63;
#pragma unroll
  for (int q = 0; q < 2; ++q) {
    int fid = wv * 2 + q;
    int nb = fid >> 1, kb = fid & 1;
    short8 o;
#pragma unroll
    for (int j = 0; j < 8; ++j)
      o[j] = (short)f2bf(tile[kb * 32 + (l >> 4) * 8 + j][nb * 16 + (l & 15)]);
    unsigned short* op = out + (((size_t)(n0 / 16 + nb) * (K / 32)) + (k0 / 32 + kb)) * 512 + l * 8;
    *(short8*)op = o;
  }
}

// ---- pass 1: u=X@W1, v=X@W3, h=silu(u)*v; BM=64 BN=64, A full-stage, B global->reg ----
__global__ __launch_bounds__(256, 2) void k_ffn1(const unsigned short* __restrict__ xb,
                                                 const unsigned short* __restrict__ w1f,
                                                 const unsigned short* __restrict__ w3f,
                                                 const int* __restrict__ cntp,
                                                 const int* __restrict__ basep,
                                                 const int* __restrict__ list,
                                                 const int* __restrict__ tl1,
                                                 const int* __restrict__ ntl,
                                                 unsigned short* __restrict__ hbuf) {
  if ((int)blockIdx.x >= ntl[0]) return;
  int pk = tl1[blockIdx.x];
  int e = pk >> 16, g0 = pk & 0xffff;
  int lim = basep[e] + cntp[e];
  int nt = blockIdx.y;
  __shared__ unsigned short sA[64 * 512];   // 64 KB, XOR-swizzled 16B slots
  int tid = threadIdx.x, wv = tid >> 6, l = tid & 63;
  int wr = wv >> 1, wc = wv & 1;

  // one-time A stage: wave wv stages rows wv*16 .. wv*16+15 (1 row = 1 KB = one gld16/wave)
#pragma unroll
  for (int it = 0; it < 16; ++it) {
    int row = wv * 16 + it;
    int gr = g0 + row; if (gr >= lim) gr = lim - 1;
    int tok = list[gr];
    int slot = (l & 56) | ((l & 7) ^ (row & 7));   // inverse-swizzled source slot
    gld16(xb + (size_t)tok * D_DIM + slot * 8, sA + row * 512);
  }

  const unsigned short* b1p = w1f + ((size_t)(e * 128 + nt * 4 + wc * 2) * 16) * 512 + l * 8;
  const unsigned short* b3p = w3f + ((size_t)(e * 128 + nt * 4 + wc * 2) * 16) * 512 + l * 8;

  f32x4 au[2][2], av[2][2];
#pragma unroll
  for (int i = 0; i < 2; ++i)
#pragma unroll
    for (int j = 0; j < 2; ++j) {
      au[i][j] = (f32x4){0.f, 0.f, 0.f, 0.f};
      av[i][j] = (f32x4){0.f, 0.f, 0.f, 0.f};
    }

  __syncthreads();   // drains gld16; the ONLY barrier

#pragma unroll 4
  for (int kk = 0; kk < 16; ++kk) {
    short8 a[2], b1[2], b3[2];
#pragma unroll
    for (int j = 0; j < 2; ++j) {
      b1[j] = *(const short8*)(b1p + (size_t)(j * 16 + kk) * 512);
      b3[j] = *(const short8*)(b3p + (size_t)(j * 16 + kk) * 512);
    }
#pragma unroll
    for (int i = 0; i < 2; ++i) {
      int r = wr * 32 + i * 16 + (l & 15);
      int slot = kk * 4 + (l >> 4);
      int swz = (slot & 56) | ((slot & 7) ^ (r & 7));
      a[i] = *(const short8*)(sA + r * 512 + swz * 8);
    }
#pragma unroll
    for (int i = 0; i < 2; ++i)
#pragma unroll
      for (int j = 0; j < 2; ++j) {
        au[i][j] = __builtin_amdgcn_mfma_f32_16x16x32_bf16(a[i], b1[j], au[i][j], 0, 0, 0);
        av[i][j] = __builtin_amdgcn_mfma_f32_16x16x32_bf16(a[i], b3[j], av[i][j], 0, 0, 0);
      }
  }

  int cloc = l & 15, rb = (l >> 4) * 4;
#pragma unroll
  for (int i = 0; i < 2; ++i)
#pragma unroll
    for (int j = 0; j < 2; ++j) {
      int col = nt * 64 + wc * 32 + j * 16 + cloc;
#pragma unroll
      for (int r = 0; r < 4; ++r) {
        int gr = g0 + wr * 32 + i * 16 + rb + r;
        if (gr < lim) {
          float uu = au[i][j][r], vv = av[i][j][r];
          float hh = (uu / (1.f + expf(-uu))) * vv;
          hbuf[(size_t)gr * F_DIM + col] = f2bf(hh);
        }
      }
    }
}

// ---- pass 2: y = h @ W2, out[tok] = w*y; BM=64 BN=64, A-chunk dbuf, B global->reg ----
__global__ __launch_bounds__(256, 4) void k_ffn2(const unsigned short* __restrict__ hbuf,
                                                 const unsigned short* __restrict__ w2f,
                                                 const int* __restrict__ cntp,
                                                 const int* __restrict__ basep,
                                                 const int* __restrict__ list,
                                                 const int* __restrict__ tl1,
                                                 const int* __restrict__ ntl,
                                                 const float* __restrict__ wbuf,
                                                 float* __restrict__ out) {
  if ((int)blockIdx.x >= ntl[0]) return;
  int pk = tl1[blockIdx.x];
  int e = pk >> 16, g0 = pk & 0xffff;
  int lim = basep[e] + cntp[e];
  int nt = blockIdx.y;
  __shared__ unsigned short sA[2 * 8192];   // 2 x 16 KB chunks [64][128], swizzled
  int tid = threadIdx.x, wv = tid >> 6, l = tid & 63;
  int wr = wv >> 1, wc = wv & 1;

  auto stage = [&](int buf, int ck) {
#pragma unroll
    for (int it = 0; it < 4; ++it) {
      int row0 = it * 16 + wv * 4;             // wave-uniform
      int row = row0 + (l >> 4);
      int gr = g0 + row; if (gr > T_TOK - 1) gr = T_TOK - 1;
      int sl = (l & 8) | ((l & 7) ^ (row & 7));
      gld16(hbuf + (size_t)gr * F_DIM + ck * 128 + sl * 8, sA + buf * 8192 + row0 * 128);
    }
  };

  const unsigned short* b2p = w2f + ((size_t)(e * 32 + nt * 4 + wc * 2) * 64) * 512 + l * 8;

  f32x4 acc[2][2];
#pragma unroll
  for (int i = 0; i < 2; ++i)
#pragma unroll
    for (int j = 0; j < 2; ++j) acc[i][j] = (f32x4){0.f, 0.f, 0.f, 0.f};

  stage(0, 0);
  __syncthreads();
  int cur = 0;
  for (int ck = 0; ck < 16; ++ck) {
    if (ck < 15) stage(cur ^ 1, ck + 1);
#pragma unroll
    for (int kk = 0; kk < 4; ++kk) {
      short8 a[2], b[2];
#pragma unroll
      for (int i = 0; i < 2; ++i) {
        int r = wr * 32 + i * 16 + (l & 15);
        int slot = kk * 4 + (l >> 4);
        int swz = (slot & 8) | ((slot & 7) ^ (r & 7));
        a[i] = *(const short8*)(sA + cur * 8192 + r * 128 + swz * 8);
      }
#pragma unroll
      for (int j = 0; j < 2; ++j)
        b[j] = *(const short8*)(b2p + (size_t)(j * 64 + ck * 4 + kk) * 512);
      acc[0][0] = __builtin_amdgcn_mfma_f32_16x16x32_bf16(a[0], b[0], acc[0][0], 0, 0, 0);
      acc[0][1] = __builtin_amdgcn_mfma_f32_16x16x32_bf16(a[0], b[1], acc[0][1], 0, 0, 0);
      acc[1][0] = __builtin_amdgcn_mfma_f32_16x16x32_bf16(a[1], b[0], acc[1][0], 0, 0, 0);
      acc[1][1] = __builtin_amdgcn_mfma_f32_16x16x32_bf16(a[1], b[1], acc[1][1], 0, 0, 0);
    }
    __syncthreads();
    cur ^= 1;
  }

  int cloc = l & 15, rb = (l >> 4) * 4;
#pragma unroll
  for (int i = 0; i < 2; ++i)
#pragma unroll
    for (int j = 0; j < 2; ++j)
#pragma unroll
      for (int r = 0; r < 4; ++r) {
        int gr = g0 + wr * 32 + i * 16 + rb + r;
        if (gr < lim) {
          int tok = list[gr];
          out[(size_t)tok * D_DIM + nt * 64 + wc * 32 + j * 16 + cloc] = wbuf[tok] * acc[i][j][r];
        }
      }
}

// ---------------- launch ----------------
extern "C" void kernel_launch(void* const* d_in, const int* in_sizes, int n_in,
                              void* d_out, int out_size, void* d_ws, size_t ws_size,
                              hipStream_t stream) {
  const float* x  = (const float*)d_in[0];
  const float* Wg = (const float*)d_in[1];
  const float* W1 = (const float*)d_in[2];
  const float* W2 = (const float*)d_in[3];
  const float* W3 = (const float*)d_in[4];
  float* out = (float*)d_out;
  char* ws = (char*)d_ws;

  int*            jbuf  = (int*)(ws + 0);
  float*          wbuf  = (float*)(ws + 8192);
  int*            cntp  = (int*)(ws + 16384);
  int*            basep = (int*)(ws + 16448);
  int*            list  = (int*)(ws + 16640);      // int[2048]
  int*            tl1   = (int*)(ws + 24832);      // int[40]
  int*            ntl   = (int*)(ws + 25600);      // int[2]
  unsigned short* xb    = (unsigned short*)(ws + 32768);                          // bf16 [2048][512]
  unsigned short* w1f   = (unsigned short*)(ws + 32768 + 2097152);                // frag [8][128][16][64][8]
  unsigned short* w3f   = (unsigned short*)(ws + 32768 + 2097152 + 16777216);
  unsigned short* w2f   = (unsigned short*)(ws + 32768 + 2097152 + 2 * 16777216); // frag [8][32][64][64][8]
  unsigned short* hbuf  = (unsigned short*)(ws + 32768 + 2097152 + 3 * 16777216); // bf16 [2048][2048]

  k_route<<<dim3(256), dim3(256), 0, stream>>>(x, Wg, jbuf, wbuf, xb);
  k_bucket<<<dim3(1), dim3(256), 0, stream>>>(jbuf, cntp, basep, list, tl1, ntl);
  k_wfrag<<<dim3(32, 8, 16), dim3(256), 0, stream>>>(W1, W3, w1f, w3f, 512, 2048);
  k_wfrag<<<dim3(8, 32, 8), dim3(256), 0, stream>>>(W2, W2, w2f, w2f, 2048, 512);
  k_ffn1<<<dim3(MAXT1, 32), dim3(256), 0, stream>>>(xb, w1f, w3f, cntp, basep, list, tl1, ntl, hbuf);
  k_ffn2<<<dim3(MAXT1, 8), dim3(256), 0, stream>>>(hbuf, w2f, cntp, basep, list, tl1, ntl, wbuf, out);
}

// Round 5
// 98.118 us; speedup vs baseline: 2.6439x; 1.1088x over previous
//
#include <hip/hip_runtime.h>
#include <hip/hip_bf16.h>
#include <math.h>

typedef __attribute__((ext_vector_type(8))) short short8;
typedef __attribute__((ext_vector_type(4))) float f32x4;

#define T_TOK 2048
#define D_DIM 512
#define F_DIM 2048
#define E_NUM 8
#define MAXT1 40   // >= sum_e ceil(cnt_e/64) <= 32+7

__device__ __forceinline__ unsigned short f2bf(float f) {
  union { float f; unsigned u; } c; c.f = f;
  unsigned u = c.u;
  return (unsigned short)((u + 0x7fffu + ((u >> 16) & 1u)) >> 16);
}

__device__ __forceinline__ void gld16(const void* g, void* l) {
  __builtin_amdgcn_global_load_lds((const __attribute__((address_space(1))) int*)g,
                                   (__attribute__((address_space(3))) int*)l, 16, 0, 0);
}

// ---- routing: logits (32-way K-split) + top-2 + weight; also converts x->bf16 ----
__global__ __launch_bounds__(256) void k_route(const float* __restrict__ x,
                                               const float* __restrict__ Wg,
                                               int* __restrict__ jbuf,
                                               float* __restrict__ wbuf,
                                               unsigned short* __restrict__ xb) {
  int gid = blockIdx.x * 256 + threadIdx.x;
  int t = gid >> 5, seg = gid & 31;
  const float* xp = x + (size_t)t * D_DIM + seg * 16;
  unsigned short* xo = xb + (size_t)t * D_DIM + seg * 16;
  float acc[8];
#pragma unroll
  for (int e = 0; e < 8; ++e) acc[e] = 0.f;
#pragma unroll
  for (int i = 0; i < 4; ++i) {
    float4 v = *(const float4*)(xp + i * 4);
    ushort4 o;
    o.x = f2bf(v.x); o.y = f2bf(v.y); o.z = f2bf(v.z); o.w = f2bf(v.w);
    *(ushort4*)(xo + i * 4) = o;
    const float* xs = (const float*)&v;
#pragma unroll
    for (int q = 0; q < 4; ++q) {
      int d = seg * 16 + i * 4 + q;
      const float4* wr = (const float4*)(Wg + (size_t)d * 8);
      float4 w0 = wr[0], w1 = wr[1];
      acc[0] += xs[q] * w0.x; acc[1] += xs[q] * w0.y;
      acc[2] += xs[q] * w0.z; acc[3] += xs[q] * w0.w;
      acc[4] += xs[q] * w1.x; acc[5] += xs[q] * w1.y;
      acc[6] += xs[q] * w1.z; acc[7] += xs[q] * w1.w;
    }
  }
#pragma unroll
  for (int off = 1; off < 32; off <<= 1)
#pragma unroll
    for (int e = 0; e < 8; ++e) acc[e] += __shfl_xor(acc[e], off);
  if (seg == 0) {
    float l0 = -1e30f, l1 = -1e30f; int i0 = 0, i1 = 0;
#pragma unroll
    for (int e = 0; e < 8; ++e) {
      float l = acc[e];
      if (l > l0) { l1 = l0; i1 = i0; l0 = l; i0 = e; }
      else if (l > l1) { l1 = l; i1 = e; }
    }
    int j; float w;
    if (i0 > i1) { j = i0; w = 1.f / (1.f + expf(l1 - l0)); }
    else         { j = i1; w = 1.f / (1.f + expf(l0 - l1)); }
    jbuf[t] = j; wbuf[t] = w;
  }
}

// ---- bucket: counts, bases, compact token list, compact tile list (BM=64) ----
__global__ __launch_bounds__(256) void k_bucket(const int* __restrict__ jbuf,
                                                int* __restrict__ cntp,
                                                int* __restrict__ basep,
                                                int* __restrict__ list,
                                                int* __restrict__ tl1,
                                                int* __restrict__ ntl) {
  __shared__ int scnt[8], scur[8];
  int tid = threadIdx.x;
  if (tid < 8) scnt[tid] = 0;
  __syncthreads();
  for (int t = tid; t < T_TOK; t += 256) atomicAdd(&scnt[jbuf[t]], 1);
  __syncthreads();
  if (tid == 0) {
    int run = 0;
    for (int e = 0; e < 8; ++e) {
      cntp[e] = scnt[e]; basep[e] = run; scur[e] = run;
      run += scnt[e];
    }
    int n1 = 0, bb = 0;
    for (int e = 0; e < 8; ++e) {
      for (int m = 0; m < scnt[e]; m += 64) tl1[n1++] = (e << 16) | (bb + m);
      bb += scnt[e];
    }
    ntl[0] = n1;
  }
  __syncthreads();
  for (int t = tid; t < T_TOK; t += 256) {
    int j = jbuf[t];
    int p = atomicAdd(&scur[j], 1);
    list[p] = t;
  }
}

// ---- weight reformat: [Z][K][N] f32 -> fragment-major bf16 [Z][N/16][K/32][64][8] ----
__global__ __launch_bounds__(256) void k_wfrag(const float* __restrict__ inA,
                                               const float* __restrict__ inB,
                                               unsigned short* __restrict__ outA,
                                               unsigned short* __restrict__ outB,
                                               int K, int N) {
  __shared__ float tile[64][65];
  int z = blockIdx.z;
  const float* in; unsigned short* out;
  size_t zsz = (size_t)(K / 32) * (N / 16) * 512;
  if (z < 8) { in = inA + (size_t)z * K * N;       out = outA + (size_t)z * zsz; }
  else       { in = inB + (size_t)(z - 8) * K * N; out = outB + (size_t)(z - 8) * zsz; }
  int n0 = blockIdx.x * 64, k0 = blockIdx.y * 64;
  int tid = threadIdx.x;
  int lr = tid >> 4, lc = tid & 15;
#pragma unroll
  for (int it = 0; it < 4; ++it) {
    int row = it * 16 + lr;
    float4 v = *(const float4*)(in + (size_t)(k0 + row) * N + n0 + lc * 4);
    tile[row][lc * 4 + 0] = v.x;
    tile[row][lc * 4 + 1] = v.y;
    tile[row][lc * 4 + 2] = v.z;
    tile[row][lc * 4 + 3] = v.w;
  }
  __syncthreads();
  int wv = tid >> 6, l = tid & 63;
#pragma unroll
  for (int q = 0; q < 2; ++q) {
    int fid = wv * 2 + q;
    int nb = fid >> 1, kb = fid & 1;
    short8 o;
#pragma unroll
    for (int j = 0; j < 8; ++j)
      o[j] = (short)f2bf(tile[kb * 32 + (l >> 4) * 8 + j][nb * 16 + (l & 15)]);
    unsigned short* op = out + (((size_t)(n0 / 16 + nb) * (K / 32)) + (k0 / 32 + kb)) * 512 + l * 8;
    *(short8*)op = o;
  }
}

// ---- pass 1: B-panel in registers, loop over m-tiles; BM=64 BN=32 ----
__global__ __launch_bounds__(256, 2) void k_ffn1(const unsigned short* __restrict__ xb,
                                                 const unsigned short* __restrict__ w1f,
                                                 const unsigned short* __restrict__ w3f,
                                                 const int* __restrict__ cntp,
                                                 const int* __restrict__ basep,
                                                 const int* __restrict__ list,
                                                 unsigned short* __restrict__ hbuf) {
  int e = blockIdx.x & 7, np = blockIdx.x >> 3;   // np: 64 panels of 32 cols
  int cnt = cntp[e];
  if (cnt == 0) return;
  int base = basep[e];
  int nm = (cnt + 63) >> 6;
  __shared__ unsigned short sA[64 * 512];   // 64 KB, XOR-swizzled 16B slots
  int tid = threadIdx.x, wv = tid >> 6, l = tid & 63;
  int wr = wv >> 1, wc = wv & 1;

  // B fragments for this wave's 16-col block, all K: loaded once, stay in registers
  const unsigned short* bp1 = w1f + ((size_t)(e * 128 + np * 2 + wc) * 16) * 512 + l * 8;
  const unsigned short* bp3 = w3f + ((size_t)(e * 128 + np * 2 + wc) * 16) * 512 + l * 8;
  short8 B1[16], B3[16];
#pragma unroll
  for (int k = 0; k < 16; ++k) {
    B1[k] = *(const short8*)(bp1 + (size_t)k * 512);
    B3[k] = *(const short8*)(bp3 + (size_t)k * 512);
  }

  for (int im = 0; im < nm; ++im) {
    int g0 = base + im * 64;
    int lim = base + cnt;
    // stage A tile [64][512] (wave wv: rows wv*16..+15), swizzled source slots
#pragma unroll
    for (int it = 0; it < 16; ++it) {
      int row = wv * 16 + it;
      int gr = g0 + row; if (gr >= lim) gr = lim - 1;
      int tok = list[gr];
      int slot = (l & 56) | ((l & 7) ^ (row & 7));
      gld16(xb + (size_t)tok * D_DIM + slot * 8, sA + row * 512);
    }
    __syncthreads();   // drain gld16, publish sA

    f32x4 au[2], av[2];
#pragma unroll
    for (int i = 0; i < 2; ++i) {
      au[i] = (f32x4){0.f, 0.f, 0.f, 0.f};
      av[i] = (f32x4){0.f, 0.f, 0.f, 0.f};
    }
#pragma unroll
    for (int kf = 0; kf < 16; ++kf) {
      short8 a[2];
#pragma unroll
      for (int i = 0; i < 2; ++i) {
        int r = wr * 32 + i * 16 + (l & 15);
        int slot = kf * 4 + (l >> 4);
        int swz = (slot & 56) | ((slot & 7) ^ (r & 7));
        a[i] = *(const short8*)(sA + r * 512 + swz * 8);
      }
#pragma unroll
      for (int i = 0; i < 2; ++i) {
        au[i] = __builtin_amdgcn_mfma_f32_16x16x32_bf16(a[i], B1[kf], au[i], 0, 0, 0);
        av[i] = __builtin_amdgcn_mfma_f32_16x16x32_bf16(a[i], B3[kf], av[i], 0, 0, 0);
      }
    }
    __syncthreads();   // all LDS reads done before next m-iter restages

    int cloc = l & 15, rb = (l >> 4) * 4;
    int col = np * 32 + wc * 16 + cloc;
#pragma unroll
    for (int i = 0; i < 2; ++i)
#pragma unroll
      for (int r = 0; r < 4; ++r) {
        int gr = g0 + wr * 32 + i * 16 + rb + r;
        if (gr < lim) {
          float uu = au[i][r], vv = av[i][r];
          float hh = (uu / (1.f + expf(-uu))) * vv;
          hbuf[(size_t)gr * F_DIM + col] = f2bf(hh);
        }
      }
  }
}

// ---- pass 2: y = h @ W2, out[tok]=w*y; BM=64 BN=64, A dbuf + B ping-pong prefetch ----
__global__ __launch_bounds__(256, 3) void k_ffn2(const unsigned short* __restrict__ hbuf,
                                                 const unsigned short* __restrict__ w2f,
                                                 const int* __restrict__ cntp,
                                                 const int* __restrict__ basep,
                                                 const int* __restrict__ list,
                                                 const int* __restrict__ tl1,
                                                 const int* __restrict__ ntl,
                                                 const float* __restrict__ wbuf,
                                                 float* __restrict__ out) {
  if ((int)blockIdx.x >= ntl[0]) return;
  int pk = tl1[blockIdx.x];
  int e = pk >> 16, g0 = pk & 0xffff;
  int lim = basep[e] + cntp[e];
  int nt = blockIdx.y;
  __shared__ unsigned short sA[2 * 8192];   // 2 x 16 KB chunks [64][128], swizzled
  int tid = threadIdx.x, wv = tid >> 6, l = tid & 63;
  int wr = wv >> 1, wc = wv & 1;

  auto stage = [&](int buf, int ck) {
#pragma unroll
    for (int it = 0; it < 4; ++it) {
      int row0 = it * 16 + wv * 4;             // wave-uniform
      int row = row0 + (l >> 4);
      int gr = g0 + row; if (gr > T_TOK - 1) gr = T_TOK - 1;
      int sl = (l & 8) | ((l & 7) ^ (row & 7));
      gld16(hbuf + (size_t)gr * F_DIM + ck * 128 + sl * 8, sA + buf * 8192 + row0 * 128);
    }
  };

  const unsigned short* b2p = w2f + ((size_t)(e * 32 + nt * 4 + wc * 2) * 64) * 512 + l * 8;

  short8 Ba[8], Bb[8];
  auto loadB = [&](short8* B, int ck) {
#pragma unroll
    for (int kk = 0; kk < 4; ++kk)
#pragma unroll
      for (int j = 0; j < 2; ++j)
        B[kk * 2 + j] = *(const short8*)(b2p + (size_t)(j * 64 + ck * 4 + kk) * 512);
  };

  f32x4 acc[2][2];
#pragma unroll
  for (int i = 0; i < 2; ++i)
#pragma unroll
    for (int j = 0; j < 2; ++j) acc[i][j] = (f32x4){0.f, 0.f, 0.f, 0.f};

  auto compute = [&](const short8* B, int cur) {
#pragma unroll
    for (int kk = 0; kk < 4; ++kk) {
      short8 a[2];
#pragma unroll
      for (int i = 0; i < 2; ++i) {
        int r = wr * 32 + i * 16 + (l & 15);
        int slot = kk * 4 + (l >> 4);
        int swz = (slot & 8) | ((slot & 7) ^ (r & 7));
        a[i] = *(const short8*)(sA + cur * 8192 + r * 128 + swz * 8);
      }
      acc[0][0] = __builtin_amdgcn_mfma_f32_16x16x32_bf16(a[0], B[kk * 2 + 0], acc[0][0], 0, 0, 0);
      acc[0][1] = __builtin_amdgcn_mfma_f32_16x16x32_bf16(a[0], B[kk * 2 + 1], acc[0][1], 0, 0, 0);
      acc[1][0] = __builtin_amdgcn_mfma_f32_16x16x32_bf16(a[1], B[kk * 2 + 0], acc[1][0], 0, 0, 0);
      acc[1][1] = __builtin_amdgcn_mfma_f32_16x16x32_bf16(a[1], B[kk * 2 + 1], acc[1][1], 0, 0, 0);
    }
  };

  stage(0, 0);
  loadB(Ba, 0);
  __syncthreads();
  int cur = 0;
  for (int ck = 0; ck < 16; ck += 2) {
    // even step: prefetch ck+1 (A into buf^1, B into Bb), compute ck from Ba
    stage(cur ^ 1, ck + 1);
    loadB(Bb, ck + 1);
    compute(Ba, cur);
    __syncthreads();
    cur ^= 1;
    // odd step: prefetch ck+2, compute ck+1 from Bb
    if (ck + 2 < 16) {
      stage(cur ^ 1, ck + 2);
      loadB(Ba, ck + 2);
    }
    compute(Bb, cur);
    __syncthreads();
    cur ^= 1;
  }

  int cloc = l & 15, rb = (l >> 4) * 4;
#pragma unroll
  for (int i = 0; i < 2; ++i)
#pragma unroll
    for (int j = 0; j < 2; ++j)
#pragma unroll
      for (int r = 0; r < 4; ++r) {
        int gr = g0 + wr * 32 + i * 16 + rb + r;
        if (gr < lim) {
          int tok = list[gr];
          out[(size_t)tok * D_DIM + nt * 64 + wc * 32 + j * 16 + cloc] = wbuf[tok] * acc[i][j][r];
        }
      }
}

// ---------------- launch ----------------
extern "C" void kernel_launch(void* const* d_in, const int* in_sizes, int n_in,
                              void* d_out, int out_size, void* d_ws, size_t ws_size,
                              hipStream_t stream) {
  const float* x  = (const float*)d_in[0];
  const float* Wg = (const float*)d_in[1];
  const float* W1 = (const float*)d_in[2];
  const float* W2 = (const float*)d_in[3];
  const float* W3 = (const float*)d_in[4];
  float* out = (float*)d_out;
  char* ws = (char*)d_ws;

  int*            jbuf  = (int*)(ws + 0);
  float*          wbuf  = (float*)(ws + 8192);
  int*            cntp  = (int*)(ws + 16384);
  int*            basep = (int*)(ws + 16448);
  int*            list  = (int*)(ws + 16640);      // int[2048]
  int*            tl1   = (int*)(ws + 24832);      // int[40]
  int*            ntl   = (int*)(ws + 25600);      // int[2]
  unsigned short* xb    = (unsigned short*)(ws + 32768);                          // bf16 [2048][512]
  unsigned short* w1f   = (unsigned short*)(ws + 32768 + 2097152);                // frag [8][128][16][64][8]
  unsigned short* w3f   = (unsigned short*)(ws + 32768 + 2097152 + 16777216);
  unsigned short* w2f   = (unsigned short*)(ws + 32768 + 2097152 + 2 * 16777216); // frag [8][32][64][64][8]
  unsigned short* hbuf  = (unsigned short*)(ws + 32768 + 2097152 + 3 * 16777216); // bf16 [2048][2048]

  k_route<<<dim3(256), dim3(256), 0, stream>>>(x, Wg, jbuf, wbuf, xb);
  k_bucket<<<dim3(1), dim3(256), 0, stream>>>(jbuf, cntp, basep, list, tl1, ntl);
  k_wfrag<<<dim3(32, 8, 16), dim3(256), 0, stream>>>(W1, W3, w1f, w3f, 512, 2048);
  k_wfrag<<<dim3(8, 32, 8), dim3(256), 0, stream>>>(W2, W2, w2f, w2f, 2048, 512);
  k_ffn1<<<dim3(512), dim3(256), 0, stream>>>(xb, w1f, w3f, cntp, basep, list, hbuf);
  k_ffn2<<<dim3(MAXT1, 8), dim3(256), 0, stream>>>(hbuf, w2f, cntp, basep, list, tl1, ntl, wbuf, out);
}